// Round 1
// baseline (257.004 us; speedup 1.0000x reference)
//
#include <hip/hip_runtime.h>
#include <math.h>

// ---------------- problem constants ----------------
#define T_LEN   32768
#define NK      192
#define NB      2
#define KDIR    48            // k < KDIR (j<=2): exact direct conv path
#define MAXM    56            // max half-support for direct path (true max 50)
#define BBLK    9216          // block-path blocks (j=7..11), one output each, both batches
#define WBLK    3872          // wave-path blocks (j=3..6), 4 waves x 8 outputs, both batches
#define GRIDX   (BBLK + WBLK)

struct SParams {
  int m1e[144];   // even half-support of stage-1 kernel per k-48
  int voff[144];  // v-table word offset per k-48
  int slot[144];  // padded complex tap count per k-48 (zero-filled tail)
  int ab[9];      // A-arena word base per octave j-3
};

__device__ __forceinline__ int j2_of_q(int q) {
  // ceil(3.25 * 2^(q/16)) : {4,...,4,5,...,5,6,...,6,7}
  return 4 + (q >= 5) + (q >= 10) + (q >= 15);
}

// ---------------- v-table: v[m] = g1(m) * e^{i*omega*m} / N1 ----------------
__global__ __launch_bounds__(256) void k_vtab(float* __restrict__ ws, SParams P) {
  int ki = blockIdx.y;                 // 0..143
  int slotc = P.slot[ki];
  int M1e = P.m1e[ki];
  float* dst = ws + P.voff[ki];
  int nent = 2 * M1e + 2;              // m in [-M1e, M1e+1]
  int k = ki + 48;
  int j = k >> 4, q = k & 15;
  float sig = 2.f * exp2f((float)(16 * j + q) * 0.0625f);
  float s1 = sig * 0.86602540378f;
  float gc = -0.5f / (s1 * s1);
  float om = 6.28318530718f / sig;
  float norm = 1.f / (2.50662827463f * s1 * erff((float)M1e / (1.41421356237f * s1)));
  #pragma unroll
  for (int e0 = 0; e0 < 4; ++e0) {
    int e = blockIdx.x * 1024 + e0 * 256 + threadIdx.x;
    if (e >= slotc) continue;
    if (e >= nent) { dst[2 * e] = 0.f; dst[2 * e + 1] = 0.f; continue; }
    float mm = (float)(e - M1e);
    float g = __expf(gc * mm * mm) * norm;
    float sn, cs; __sincosf(om * mm, &sn, &cs);
    dst[2 * e] = g * cs;
    dst[2 * e + 1] = g * sn;
  }
}

// ---------------- merged stage 1, both batches per block ----------------
// Block path (j=7..11): one output per 256-thread block, 512 taps/iter.
// Wave path (j=3..6): wave = 8 phases x 8 outputs, 16 taps/iter.
// Interior iterations (no boundary clamping needed) run a software-pipelined
// A/B double-buffered loop: 12 loads in flight while FMAing previous 12.
// Boundary iterations (head/tail) keep the clamped scalar path.

#define FMA1(V,A,B) \
  ar0 += V.x*A.x; ai0 += V.y*A.x; ar0 += V.z*A.y; ai0 += V.w*A.y; \
  ar1 += V.x*B.x; ai1 += V.y*B.x; ar1 += V.z*B.y; ai1 += V.w*B.y;

#define LOADQ(S_, ST) \
  v##S_##0 = vq[0]; v##S_##1 = vq[(ST)]; v##S_##2 = vq[2*(ST)]; v##S_##3 = vq[3*(ST)]; \
  a##S_##0 = xa[0]; a##S_##1 = xa[(ST)]; a##S_##2 = xa[2*(ST)]; a##S_##3 = xa[3*(ST)]; \
  b##S_##0 = xv2[0]; b##S_##1 = xv2[(ST)]; b##S_##2 = xv2[2*(ST)]; b##S_##3 = xv2[3*(ST)]; \
  vq += 4*(ST); xa += 4*(ST); xv2 += 4*(ST);

#define FMAQ(S_) \
  FMA1(v##S_##0, a##S_##0, b##S_##0) FMA1(v##S_##1, a##S_##1, b##S_##1) \
  FMA1(v##S_##2, a##S_##2, b##S_##2) FMA1(v##S_##3, a##S_##3, b##S_##3)

// pipelined interior over nit iterations; ST = per-iteration stride in
// float4 (v) / float2 (x) units (block path 256, wave path 8)
#define INTERIOR(ST) \
  { \
    int nblk = nit >> 2, rem = nit & 3; \
    if (nblk > 0) { \
      float4 vA0, vA1, vA2, vA3, vB0, vB1, vB2, vB3; \
      float2 aA0, aA1, aA2, aA3, aB0, aB1, aB2, aB3; \
      float2 bA0, bA1, bA2, bA3, bB0, bB1, bB2, bB3; \
      LOADQ(A, ST); \
      int rl = nblk - 1; \
      while (rl >= 2) { \
        LOADQ(B, ST); \
        FMAQ(A); \
        LOADQ(A, ST); \
        FMAQ(B); \
        rl -= 2; \
      } \
      if (rl == 1) { LOADQ(B, ST); FMAQ(A); FMAQ(B); } \
      else { FMAQ(A); } \
    } \
    for (int s2 = 0; s2 < rem; ++s2) { \
      float4 v = vq[0]; float2 a = xa[0]; float2 b = xv2[0]; \
      FMA1(v, a, b); \
      vq += (ST); xa += (ST); xv2 += (ST); \
    } \
  }

__global__ __launch_bounds__(256) void k_s1(const float* __restrict__ x,
                                            float* __restrict__ ws, SParams P) {
  __shared__ float red[16];
  const float* xb0 = x;
  const float* xb1 = x + T_LEN;
  int bx = blockIdx.x;
  int tid = threadIdx.x;

  if (bx < BBLK) {
    // ---- block path (j=7..11), deepest first ----
    int j, base;
    if (bx < 512)       { j = 11; base = 0; }
    else if (bx < 1280) { j = 10; base = 512; }
    else if (bx < 2560) { j = 9;  base = 1280; }
    else if (bx < 4864) { j = 8;  base = 2560; }
    else                { j = 7;  base = 4864; }
    int rem0 = bx - base;
    int q = rem0 & 15, nidx = rem0 >> 4;
    int ki = 16 * (j - 3) + q;
    int d = 1 << j, J2 = j2_of_q(q);
    int M1e = P.m1e[ki];
    const float* vt = ws + P.voff[ki];
    int nd = (nidx - J2) * d;
    int ustart = nd - M1e;                  // even
    int it0 = (-ustart) >> 9; if (it0 < 0) it0 = 0;
    int itend = ((T_LEN - 1 - ustart) >> 9) + 1;
    int niter = P.slot[ki] >> 9; if (niter > itend) niter = itend;
    // interior iteration range: all 512-tap windows fully inside [0, T_LEN)
    int itA = (-ustart + 511) >> 9;
    if (itA < it0) itA = it0;
    if (itA > niter) itA = niter;
    int itB = ((T_LEN - 512 - ustart) >> 9) + 1;
    if (itB > niter) itB = niter;
    if (itB < itA) itB = itA;

    float ar0 = 0.f, ai0 = 0.f, ar1 = 0.f, ai1 = 0.f;

    // head (clamped)
    for (int it = it0; it < itA; ++it) {
      int mt = 2 * tid + (it << 9);
      float4 v = *(const float4*)(vt + 2 * mt);
      int u = ustart + mt;
      int uc = min(max(u, 0), T_LEN - 2);
      float2 pa = *(const float2*)(xb0 + uc);
      float2 pb = *(const float2*)(xb1 + uc);
      bool ok = (unsigned)u <= (unsigned)(T_LEN - 2);
      float x0 = ok ? pa.x : 0.f, x1 = ok ? pa.y : 0.f;
      float y0 = ok ? pb.x : 0.f, y1 = ok ? pb.y : 0.f;
      ar0 += v.x * x0; ai0 += v.y * x0; ar0 += v.z * x1; ai0 += v.w * x1;
      ar1 += v.x * y0; ai1 += v.y * y0; ar1 += v.z * y1; ai1 += v.w * y1;
    }
    // interior (pipelined, no clamps)
    {
      const float4* vq = (const float4*)vt + tid + (itA << 8);
      const float2* xa = (const float2*)xb0 + (ustart >> 1) + tid + (itA << 8);
      const float2* xv2 = (const float2*)xb1 + (ustart >> 1) + tid + (itA << 8);
      int nit = itB - itA;
      INTERIOR(256)
    }
    // tail (clamped)
    for (int it = itB; it < niter; ++it) {
      int mt = 2 * tid + (it << 9);
      float4 v = *(const float4*)(vt + 2 * mt);
      int u = ustart + mt;
      int uc = min(max(u, 0), T_LEN - 2);
      float2 pa = *(const float2*)(xb0 + uc);
      float2 pb = *(const float2*)(xb1 + uc);
      bool ok = (unsigned)u <= (unsigned)(T_LEN - 2);
      float x0 = ok ? pa.x : 0.f, x1 = ok ? pa.y : 0.f;
      float y0 = ok ? pb.x : 0.f, y1 = ok ? pb.y : 0.f;
      ar0 += v.x * x0; ai0 += v.y * x0; ar0 += v.z * x1; ai0 += v.w * x1;
      ar1 += v.x * y0; ai1 += v.y * y0; ar1 += v.z * y1; ai1 += v.w * y1;
    }
#define RED4(s_) ar0 += __shfl_xor(ar0, s_, 64); ai0 += __shfl_xor(ai0, s_, 64); \
                 ar1 += __shfl_xor(ar1, s_, 64); ai1 += __shfl_xor(ai1, s_, 64);
    RED4(1) RED4(2) RED4(4) RED4(8) RED4(16) RED4(32)
#undef RED4
    int wv = tid >> 6;
    if ((tid & 63) == 0) {
      red[4 * wv] = ar0; red[4 * wv + 1] = ai0;
      red[4 * wv + 2] = ar1; red[4 * wv + 3] = ai1;
    }
    __syncthreads();
    if (tid == 0) {
      ar0 = red[0] + red[4] + red[8] + red[12];
      ai0 = red[1] + red[5] + red[9] + red[13];
      ar1 = red[2] + red[6] + red[10] + red[14];
      ai1 = red[3] + red[7] + red[11] + red[15];
      float rev = (float)nd * exp2f(-(float)(16 * (j + 1) + q) * 0.0625f);
      rev -= floorf(rev);
      float sn, cs; __sincosf(rev * 6.28318530718f, &sn, &cs);
      int Ncu = (32767 >> j) + 17;
      float* ap = ws + P.ab[j - 3] + (q * 2) * Ncu * 2;
      *(float2*)(ap + 2 * nidx) = make_float2(ar0 * cs - ai0 * sn, ar0 * sn + ai0 * cs);
      *(float2*)(ap + 2 * (Ncu + nidx)) = make_float2(ar1 * cs - ai1 * sn, ar1 * sn + ai1 * cs);
    }
  } else {
    // ---- wave path (j=3..6): 8 phases x 8 outputs per wave ----
    int wv = tid >> 6, lane = tid & 63;
    int wid = (bx - BBLK) * 4 + wv;
    int j, base;
    if (wid < 1056)      { j = 6; base = 0; }
    else if (wid < 3136) { j = 5; base = 1056; }
    else if (wid < 7264) { j = 4; base = 3136; }
    else                 { j = 3; base = 7264; }
    int rem0 = wid - base;
    int q = rem0 & 15, tile = rem0 >> 4;
    int ki = 16 * (j - 3) + q;
    int d = 1 << j, J2 = j2_of_q(q);
    int M1e = P.m1e[ki];
    const float* vt = ws + P.voff[ki];
    int r = lane >> 3, p = lane & 7;
    int nidx = tile * 8 + r;
    int nd = (nidx - J2) * d;
    int ustart = nd - M1e;                 // even
    int it0 = (-ustart) >> 4; if (it0 < 0) it0 = 0;
    int itend = ((T_LEN - 1 - ustart) >> 4) + 1;
    int niter = P.slot[ki] >> 4; if (niter > itend) niter = itend;
    // interior iteration range: all 16-tap windows fully inside [0, T_LEN)
    int itA = (-ustart + 15) >> 4;
    if (itA < it0) itA = it0;
    if (itA > niter) itA = niter;
    int itB = ((T_LEN - 16 - ustart) >> 4) + 1;
    if (itB > niter) itB = niter;
    if (itB < itA) itB = itA;

    float ar0 = 0.f, ai0 = 0.f, ar1 = 0.f, ai1 = 0.f;
    int pb2 = 2 * p;

    // head (clamped)
    for (int it = it0; it < itA; ++it) {
      int mt = pb2 + (it << 4);
      float4 v = *(const float4*)(vt + 2 * mt);
      int u = ustart + mt;
      int uc = min(max(u, 0), T_LEN - 2);
      float2 pa = *(const float2*)(xb0 + uc);
      float2 pbv = *(const float2*)(xb1 + uc);
      bool ok = (unsigned)u <= (unsigned)(T_LEN - 2);
      float x0 = ok ? pa.x : 0.f, x1 = ok ? pa.y : 0.f;
      float y0 = ok ? pbv.x : 0.f, y1 = ok ? pbv.y : 0.f;
      ar0 += v.x * x0; ai0 += v.y * x0; ar0 += v.z * x1; ai0 += v.w * x1;
      ar1 += v.x * y0; ai1 += v.y * y0; ar1 += v.z * y1; ai1 += v.w * y1;
    }
    // interior (pipelined, no clamps)
    {
      const float4* vq = (const float4*)vt + p + (itA << 3);
      const float2* xa = (const float2*)xb0 + (ustart >> 1) + p + (itA << 3);
      const float2* xv2 = (const float2*)xb1 + (ustart >> 1) + p + (itA << 3);
      int nit = itB - itA;
      INTERIOR(8)
    }
    // tail (clamped)
    for (int it = itB; it < niter; ++it) {
      int mt = pb2 + (it << 4);
      float4 v = *(const float4*)(vt + 2 * mt);
      int u = ustart + mt;
      int uc = min(max(u, 0), T_LEN - 2);
      float2 pa = *(const float2*)(xb0 + uc);
      float2 pbv = *(const float2*)(xb1 + uc);
      bool ok = (unsigned)u <= (unsigned)(T_LEN - 2);
      float x0 = ok ? pa.x : 0.f, x1 = ok ? pa.y : 0.f;
      float y0 = ok ? pbv.x : 0.f, y1 = ok ? pbv.y : 0.f;
      ar0 += v.x * x0; ai0 += v.y * x0; ar0 += v.z * x1; ai0 += v.w * x1;
      ar1 += v.x * y0; ai1 += v.y * y0; ar1 += v.z * y1; ai1 += v.w * y1;
    }
#define RED4(s_) ar0 += __shfl_xor(ar0, s_, 64); ai0 += __shfl_xor(ai0, s_, 64); \
                 ar1 += __shfl_xor(ar1, s_, 64); ai1 += __shfl_xor(ai1, s_, 64);
    RED4(1) RED4(2) RED4(4)
#undef RED4
    if (p == 0) {
      float rev = (float)nd * exp2f(-(float)(16 * (j + 1) + q) * 0.0625f);
      rev -= floorf(rev);
      float sn, cs; __sincosf(rev * 6.28318530718f, &sn, &cs);
      int Ncu = (32767 >> j) + 17;
      float* ap = ws + P.ab[j - 3] + (q * 2) * Ncu * 2;
      *(float2*)(ap + 2 * nidx) = make_float2(ar0 * cs - ai0 * sn, ar0 * sn + ai0 * cs);
      *(float2*)(ap + 2 * (Ncu + nidx)) = make_float2(ar1 * cs - ai1 * sn, ar1 * sn + ai1 * cs);
    }
  }
}

#undef INTERIOR
#undef FMAQ
#undef LOADQ
#undef FMA1

// ---------------- stage 2: 8 outputs/thread (4 t-pos x 2 batches) ----------------
__global__ __launch_bounds__(256) void k_stage2(const float* __restrict__ ws,
                                                float* __restrict__ out, SParams P) {
  int k = KDIR + blockIdx.y;
  int j = k >> 4, q = k & 15;
  int d = 1 << j;
  int J2 = j2_of_q(q);
  float sig = 2.f * exp2f((float)(16 * j + q) * 0.0625f);
  float s2 = sig * 0.5f;
  int Ncu = (32767 >> j) + 17;
  const float* A0 = ws + P.ab[j - 3] + (q * 2) * Ncu * 2;
  const float* A1 = A0 + Ncu * 2;
  int t0 = blockIdx.x * 256 + threadIdx.x;   // [0, 8192); outputs t0 + 8192*i
  int phi = t0 & (d - 1);
  int nb0 = t0 >> j;
  int step = 8192 >> j;                      // same phi at t0 + 8192*i
  int ntap = 2 * J2 + 1;
  float fd = (float)d;
  float inv2 = 1.f / (s2 * s2);
  float u0 = (float)(phi + J2 * d);
  float eg = __expf(-0.5f * u0 * u0 * inv2);
  float mf = __expf((fd * u0 - 0.5f * fd * fd) * inv2);
  float qf = __expf(-fd * fd * inv2);
  float Z = 0.f;
  float sr0 = 0.f, si0 = 0.f, sr1 = 0.f, si1 = 0.f;
  float sr2 = 0.f, si2 = 0.f, sr3 = 0.f, si3 = 0.f;
  float tr0 = 0.f, ti0 = 0.f, tr1 = 0.f, ti1 = 0.f;
  float tr2 = 0.f, ti2 = 0.f, tr3 = 0.f, ti3 = 0.f;
  const float* Ap0 = A0 + 2 * nb0;
  const float* Ap1 = A1 + 2 * nb0;
  for (int rr = 0; rr < ntap; ++rr) {
    float w = eg; eg *= mf; mf *= qf; Z += w;
    float2 a0 = *(const float2*)(Ap0 + 2 * rr);
    float2 a1 = *(const float2*)(Ap0 + 2 * (rr + step));
    float2 a2 = *(const float2*)(Ap0 + 2 * (rr + 2 * step));
    float2 a3 = *(const float2*)(Ap0 + 2 * (rr + 3 * step));
    float2 b0 = *(const float2*)(Ap1 + 2 * rr);
    float2 b1 = *(const float2*)(Ap1 + 2 * (rr + step));
    float2 b2 = *(const float2*)(Ap1 + 2 * (rr + 2 * step));
    float2 b3 = *(const float2*)(Ap1 + 2 * (rr + 3 * step));
    sr0 += w * a0.x; si0 += w * a0.y; sr1 += w * a1.x; si1 += w * a1.y;
    sr2 += w * a2.x; si2 += w * a2.y; sr3 += w * a3.x; si3 += w * a3.y;
    tr0 += w * b0.x; ti0 += w * b0.y; tr1 += w * b1.x; ti1 += w * b1.y;
    tr2 += w * b2.x; ti2 += w * b2.y; tr3 += w * b3.x; ti3 += w * b3.y;
  }
  float zi = 1.f / Z;
  size_t ob0 = (size_t)k * T_LEN + t0;
  size_t ob1 = (size_t)(NK + k) * T_LEN + t0;
  out[ob0]         = sqrtf(sr0 * sr0 + si0 * si0) * zi;
  out[ob0 + 8192]  = sqrtf(sr1 * sr1 + si1 * si1) * zi;
  out[ob0 + 16384] = sqrtf(sr2 * sr2 + si2 * si2) * zi;
  out[ob0 + 24576] = sqrtf(sr3 * sr3 + si3 * si3) * zi;
  out[ob1]         = sqrtf(tr0 * tr0 + ti0 * ti0) * zi;
  out[ob1 + 8192]  = sqrtf(tr1 * tr1 + ti1 * ti1) * zi;
  out[ob1 + 16384] = sqrtf(tr2 * tr2 + ti2 * ti2) * zi;
  out[ob1 + 24576] = sqrtf(tr3 * tr3 + ti3 * ti3) * zi;
}

// ---------------- direct exact conv for j<=2 ----------------
__global__ __launch_bounds__(256) void k_direct(const float* __restrict__ x,
                                               const float* __restrict__ fr,
                                               const float* __restrict__ fi,
                                               float* __restrict__ out, int Lmax) {
  int k = blockIdx.y;
  int b = blockIdx.z;
  int t0 = blockIdx.x * 1024;
  int j = k >> 4, q = k & 15;
  int M = (int)ceil(6.0 * exp2((double)j + (double)q * 0.0625)) + 2; // >= true M; extra taps are 0
  int P = Lmax >> 1;
  __shared__ float xs[1024 + 2 * MAXM];
  __shared__ float frs[2 * MAXM + 1], fis[2 * MAXM + 1];
  int tid = threadIdx.x;
  int xlen = 1024 + 2 * M;
  const float* xb = x + b * T_LEN;
  for (int i = tid; i < xlen; i += 256) {
    int u = t0 - M + i;
    xs[i] = (u >= 0 && u < T_LEN) ? xb[u] : 0.f;
  }
  const float* frk = fr + (size_t)k * Lmax + (P - M);
  const float* fik = fi + (size_t)k * Lmax + (P - M);
  int tl = 2 * M + 1;
  for (int i = tid; i < tl; i += 256) { frs[i] = frk[i]; fis[i] = fik[i]; }
  __syncthreads();
  float ar[4] = {0.f, 0.f, 0.f, 0.f}, ai[4] = {0.f, 0.f, 0.f, 0.f};
  for (int tau = 0; tau < tl; ++tau) {
    float wr = frs[tau], wi = fis[tau];
    #pragma unroll
    for (int tt = 0; tt < 4; ++tt) {
      float xv = xs[tid + tt * 256 + tau];
      ar[tt] += wr * xv; ai[tt] += wi * xv;
    }
  }
  size_t ob = (size_t)(b * NK + k) * T_LEN + t0 + tid;
  #pragma unroll
  for (int tt = 0; tt < 4; ++tt)
    out[ob + tt * 256] = sqrtf(ar[tt] * ar[tt] + ai[tt] * ai[tt]);
}

// ---------------- launch ----------------
extern "C" void kernel_launch(void* const* d_in, const int* in_sizes, int n_in,
                              void* d_out, int out_size, void* d_ws, size_t ws_size,
                              hipStream_t stream) {
  const float* x  = (const float*)d_in[0];
  const float* fr = (const float*)d_in[1];
  const float* fi = (const float*)d_in[2];
  float* out = (float*)d_out;
  float* ws  = (float*)d_ws;
  int Lmax = in_sizes[1] / NK;   // 47069

  // host-side geometry (pure CPU math, deterministic, graph-capture-safe)
  SParams Pm;
  int cur = 0, maxslot = 0;
  for (int ki = 0; ki < 144; ++ki) {
    int j = (ki + 48) >> 4, q = ki & 15;
    double sig = 2.0 * exp2(((double)(16 * j + q)) / 16.0);
    double s1 = sig * 0.86602540378443864676;
    int M1 = (int)ceil(3.5 * s1);
    int M1e = (M1 + 1) & ~1;
    int R = (j >= 7) ? 512 : 16;              // tap granularity: block path 512, wave 16
    int slotc = (2 * M1e + 2 + R - 1) & ~(R - 1);
    Pm.m1e[ki] = M1e;
    Pm.voff[ki] = cur;
    Pm.slot[ki] = slotc;
    if (slotc > maxslot) maxslot = slotc;
    cur += 2 * slotc;
  }
  for (int j = 3; j <= 11; ++j) {
    Pm.ab[j - 3] = cur;
    cur += 32 * ((32767 >> j) + 17) * 2;   // 16q * 2b * Ncu * 2 words
  }

  k_vtab<<<dim3((maxslot + 1023) / 1024, 144), dim3(256), 0, stream>>>(ws, Pm);
  k_s1<<<dim3(GRIDX), dim3(256), 0, stream>>>(x, ws, Pm);
  k_direct<<<dim3(T_LEN / 1024, KDIR, NB), dim3(256), 0, stream>>>(x, fr, fi, out, Lmax);
  k_stage2<<<dim3(T_LEN / (256 * 4), NK - KDIR), dim3(256), 0, stream>>>(ws, out, Pm);
}

// Round 2
// 250.846 us; speedup vs baseline: 1.0245x; 1.0245x over previous
//
#include <hip/hip_runtime.h>
#include <math.h>

// ---------------- problem constants ----------------
#define T_LEN   32768
#define NK      192
#define NB      2
#define KDIR    48            // k < KDIR (j<=2): exact direct conv path
#define MAXM    56            // max half-support for direct path (true max 48)

struct SParams {
  int m1e[144];   // even half-support of stage-1 kernel per k-48
  int voff[144];  // v-table word offset per k-48
  int slot[144];  // padded complex tap count per k-48 (zero-filled tail, mult of 512)
  int ab[9];      // A-arena word base per octave j-3
  int jb[10];     // block-range bases, order j=11..3 (monotonic), jb[9]=grid
};

__device__ __forceinline__ int j2_of_q(int q) {
  // ceil(3.25 * 2^(q/16)) : {4,...,4,5,...,5,6,...,6,7}
  return 4 + (q >= 5) + (q >= 10) + (q >= 15);
}

// ---------------- v-table: v[m] = g1(m) * e^{i*omega*m} / N1 ----------------
__global__ __launch_bounds__(256) void k_vtab(float* __restrict__ ws, SParams P) {
  int ki = blockIdx.y;                 // 0..143
  int slotc = P.slot[ki];
  int M1e = P.m1e[ki];
  float* dst = ws + P.voff[ki];
  int nent = 2 * M1e + 2;              // m in [-M1e, M1e+1]
  int k = ki + 48;
  int j = k >> 4, q = k & 15;
  float sig = 2.f * exp2f((float)(16 * j + q) * 0.0625f);
  float s1 = sig * 0.86602540378f;
  float gc = -0.5f / (s1 * s1);
  float om = 6.28318530718f / sig;
  float norm = 1.f / (2.50662827463f * s1 * erff((float)M1e / (1.41421356237f * s1)));
  #pragma unroll
  for (int e0 = 0; e0 < 4; ++e0) {
    int e = blockIdx.x * 1024 + e0 * 256 + threadIdx.x;
    if (e >= slotc) continue;
    if (e >= nent) { dst[2 * e] = 0.f; dst[2 * e + 1] = 0.f; continue; }
    float mm = (float)(e - M1e);
    float g = __expf(gc * mm * mm) * norm;
    float sn, cs; __sincosf(om * mm, &sn, &cs);
    dst[2 * e] = g * cs;
    dst[2 * e + 1] = g * sn;
  }
}

// ================= stage 1, traffic-minimized =================
// deep path (j=7..11): block = (j,q, G consecutive outputs). x window staged in
// LDS (interleaved (xa,xb) float2 per sample); v streamed once, reused G times.
// small path (j=3..6): thread-per-(output,batch); x staged in two padded LDS planes.

template<int J, int G, int E>
__device__ __forceinline__ void deep_path(const float* __restrict__ x,
                                          float* __restrict__ ws, const SParams& P,
                                          int q, int tile, int tid,
                                          float* xs, float* red) {
  constexpr int d = 1 << J;
  constexpr int W = E + (G - 1) * d + 2;     // staged samples (even)
  const int ki = 16 * (J - 3) + q;
  const int J2 = j2_of_q(q);
  const int M1e = P.m1e[ki];
  const int slot = P.slot[ki];
  const float* vt = ws + P.voff[ki];
  const int n0 = tile * G;
  const int ubase0 = (n0 - J2) * d - M1e;    // u at e=0, g=0 (even)
  const float* xb0 = x;
  const float* xb1 = x + T_LEN;

  float acc[4 * G];
  #pragma unroll
  for (int i = 0; i < 4 * G; ++i) acc[i] = 0.f;

  for (int e0 = 0; e0 < slot; e0 += E) {
    int ub = ubase0 + e0;
    if (ub >= T_LEN || ub + W <= 0) continue;   // uniform across block
    int Ech = slot - e0; if (Ech > E) Ech = E;
    int Wn = Ech + (G - 1) * d + 2;
    int Wh = (Wn + 1) >> 1;
    // stage: xs float4 i = samples (2i, 2i+1) as (xa0, xb0, xa1, xb1)
    for (int i = tid; i < Wh; i += 256) {
      int u0 = ub + 2 * i;                      // even
      bool ok = (unsigned)u0 <= (unsigned)(T_LEN - 2);
      int uc = ok ? u0 : 0;
      float2 a = *(const float2*)(xb0 + uc);
      float2 b = *(const float2*)(xb1 + uc);
      float4 w;
      w.x = ok ? a.x : 0.f; w.y = ok ? b.x : 0.f;
      w.z = ok ? a.y : 0.f; w.w = ok ? b.y : 0.f;
      *(float4*)(xs + 4 * i) = w;
    }
    __syncthreads();
    int pend = Ech >> 9;                        // 512 taps per pass
    const float4* xp0 = (const float4*)xs + tid;
    const float* vte = vt + 2 * e0 + 4 * tid;
    for (int ps = 0; ps < pend; ++ps) {
      float4 v = *(const float4*)(vte + (ps << 10));
      const float4* xp = xp0 + (ps << 8);
      #pragma unroll
      for (int g = 0; g < G; ++g) {
        float4 xv = xp[g * (d >> 1)];
        acc[4 * g + 0] += v.x * xv.x + v.z * xv.z;   // ar0
        acc[4 * g + 1] += v.y * xv.x + v.w * xv.z;   // ai0
        acc[4 * g + 2] += v.x * xv.y + v.z * xv.w;   // ar1
        acc[4 * g + 3] += v.y * xv.y + v.w * xv.w;   // ai1
      }
    }
    __syncthreads();
  }

  // block-wide reduction of 4G values
  #pragma unroll
  for (int st = 1; st < 64; st <<= 1) {
    #pragma unroll
    for (int i = 0; i < 4 * G; ++i) acc[i] += __shfl_xor(acc[i], st, 64);
  }
  int wv = tid >> 6;
  if ((tid & 63) == 0) {
    #pragma unroll
    for (int gg = 0; gg < G; ++gg)
      *(float4*)(red + wv * 64 + 4 * gg) =
        make_float4(acc[4 * gg], acc[4 * gg + 1], acc[4 * gg + 2], acc[4 * gg + 3]);
  }
  __syncthreads();
  if (tid < 4 * G)
    red[256 + tid] = red[tid] + red[64 + tid] + red[128 + tid] + red[192 + tid];
  __syncthreads();
  if (tid < G) {
    int nidx = n0 + tid;
    int Ncu = (32767 >> J) + 17;
    if (nidx < Ncu) {
      float ar0 = red[256 + 4 * tid], ai0 = red[256 + 4 * tid + 1];
      float ar1 = red[256 + 4 * tid + 2], ai1 = red[256 + 4 * tid + 3];
      float ndf = (float)((nidx - J2) * d);
      float rev = ndf * exp2f(-(float)(16 * (J + 1) + q) * 0.0625f);
      rev -= floorf(rev);
      float sn, cs; __sincosf(rev * 6.28318530718f, &sn, &cs);
      float* ap = ws + P.ab[J - 3] + (q * 2) * Ncu * 2;
      *(float2*)(ap + 2 * nidx) = make_float2(ar0 * cs - ai0 * sn, ar0 * sn + ai0 * cs);
      *(float2*)(ap + 2 * (Ncu + nidx)) = make_float2(ar1 * cs - ai1 * sn, ar1 * sn + ai1 * cs);
    }
  }
}

template<int J, int TOUT>
__device__ __forceinline__ void small_path(const float* __restrict__ x,
                                           float* __restrict__ ws, const SParams& P,
                                           int q, int tile, int tid,
                                           float* xs, float* red) {
  constexpr int d = 1 << J;
  const int ki = 16 * (J - 3) + q;
  const int J2 = j2_of_q(q);
  const int M1e = P.m1e[ki];
  const int nent = 2 * M1e + 2;               // even
  const float* vt = ws + P.voff[ki];
  const int Ncu = (32767 >> J) + 17;
  const int o0 = tile * TOUT;
  const int ub = (o0 - J2) * d - M1e;
  const int W = (TOUT - 1) * d + nent;
  const int PS = W + (((W - 1) >> J) << 1) + 4;   // plane stride (floats)
  const float* xb0 = x;
  const float* xb1 = x + T_LEN;
  // stage both planes; addr(s) = s + 2*(s>>J) (pad 2 floats per d; even-s b64
  // reads never straddle a pad since s stays even and d is even)
  for (int i = tid; i < W; i += 256) {
    int u = ub + i;
    bool ok = (unsigned)u < (unsigned)T_LEN;
    int uc = ok ? u : 0;
    float a = xb0[uc]; a = ok ? a : 0.f;
    float bv = xb1[uc]; bv = ok ? bv : 0.f;
    int ad = i + ((i >> J) << 1);
    xs[ad] = a; xs[PS + ad] = bv;
  }
  __syncthreads();
  int th = (TOUT == 128) ? tid : (tid & 127);
  int o = th & (TOUT - 1);
  int b = th / TOUT;
  int half = (TOUT == 64) ? (tid >> 7) : 0;
  int e_lo = 0, e_hi = nent;
  if (TOUT == 64) {
    int eh = (nent >> 2) << 1;
    if (half) e_lo = eh; else e_hi = eh;
  }
  const float* pl = xs + b * PS;
  int sb = o * d;                              // even
  float ar = 0.f, ai = 0.f;
  #pragma unroll 4
  for (int e = e_lo; e < e_hi; e += 2) {
    float4 v = *(const float4*)(vt + 2 * e);   // block-uniform broadcast
    int s = sb + e;
    float2 xv = *(const float2*)(pl + s + ((s >> J) << 1));
    ar += v.x * xv.x + v.z * xv.y;
    ai += v.y * xv.x + v.w * xv.y;
  }
  if (TOUT == 64) {
    if (tid >= 128) { red[2 * (tid - 128)] = ar; red[2 * (tid - 128) + 1] = ai; }
    __syncthreads();
    if (tid < 128) { ar += red[2 * tid]; ai += red[2 * tid + 1]; }
  }
  if (half == 0 && o0 + o < Ncu && (TOUT == 128 || tid < 128)) {
    int nidx = o0 + o;
    float ndf = (float)((nidx - J2) * d);
    float rev = ndf * exp2f(-(float)(16 * (J + 1) + q) * 0.0625f);
    rev -= floorf(rev);
    float sn, cs; __sincosf(rev * 6.28318530718f, &sn, &cs);
    float* ap = ws + P.ab[J - 3] + (q * 2) * Ncu * 2;
    *(float2*)(ap + 2 * (b * Ncu + nidx)) = make_float2(ar * cs - ai * sn, ar * sn + ai * cs);
  }
}

__global__ __launch_bounds__(256) void k_s1(const float* __restrict__ x,
                                            float* __restrict__ ws, SParams P) {
  __shared__ __align__(16) float xs[12292];   // 49168 B
  __shared__ __align__(16) float red[512];    // 2048 B
  int bx = blockIdx.x, tid = threadIdx.x;
  int o = 0;
  #pragma unroll
  for (int t = 1; t < 9; ++t) if (bx >= P.jb[t]) o = t;
  int j = 11 - o;
  int rem = bx - P.jb[o];
  int tile = rem >> 4, q = rem & 15;
  switch (j) {
    case 11: deep_path<11, 2, 4096>(x, ws, P, q, tile, tid, xs, red); break;
    case 10: deep_path<10, 3, 3584>(x, ws, P, q, tile, tid, xs, red); break;
    case 9:  deep_path<9, 4, 4096>(x, ws, P, q, tile, tid, xs, red); break;
    case 8:  deep_path<8, 8, 4096>(x, ws, P, q, tile, tid, xs, red); break;
    case 7:  deep_path<7, 16, 4096>(x, ws, P, q, tile, tid, xs, red); break;
    case 6:  small_path<6, 64>(x, ws, P, q, tile, tid, xs, red); break;
    case 5:  small_path<5, 128>(x, ws, P, q, tile, tid, xs, red); break;
    case 4:  small_path<4, 128>(x, ws, P, q, tile, tid, xs, red); break;
    default: small_path<3, 128>(x, ws, P, q, tile, tid, xs, red); break;
  }
}

// ---------------- stage 2: 8 outputs/thread (4 t-pos x 2 batches) ----------------
__global__ __launch_bounds__(256) void k_stage2(const float* __restrict__ ws,
                                                float* __restrict__ out, SParams P) {
  int k = KDIR + blockIdx.y;
  int j = k >> 4, q = k & 15;
  int d = 1 << j;
  int J2 = j2_of_q(q);
  float sig = 2.f * exp2f((float)(16 * j + q) * 0.0625f);
  float s2 = sig * 0.5f;
  int Ncu = (32767 >> j) + 17;
  const float* A0 = ws + P.ab[j - 3] + (q * 2) * Ncu * 2;
  const float* A1 = A0 + Ncu * 2;
  int t0 = blockIdx.x * 256 + threadIdx.x;   // [0, 8192); outputs t0 + 8192*i
  int phi = t0 & (d - 1);
  int nb0 = t0 >> j;
  int step = 8192 >> j;                      // same phi at t0 + 8192*i
  int ntap = 2 * J2 + 1;
  float fd = (float)d;
  float inv2 = 1.f / (s2 * s2);
  float u0 = (float)(phi + J2 * d);
  float eg = __expf(-0.5f * u0 * u0 * inv2);
  float mf = __expf((fd * u0 - 0.5f * fd * fd) * inv2);
  float qf = __expf(-fd * fd * inv2);
  float Z = 0.f;
  float sr0 = 0.f, si0 = 0.f, sr1 = 0.f, si1 = 0.f;
  float sr2 = 0.f, si2 = 0.f, sr3 = 0.f, si3 = 0.f;
  float tr0 = 0.f, ti0 = 0.f, tr1 = 0.f, ti1 = 0.f;
  float tr2 = 0.f, ti2 = 0.f, tr3 = 0.f, ti3 = 0.f;
  const float* Ap0 = A0 + 2 * nb0;
  const float* Ap1 = A1 + 2 * nb0;
  for (int rr = 0; rr < ntap; ++rr) {
    float w = eg; eg *= mf; mf *= qf; Z += w;
    float2 a0 = *(const float2*)(Ap0 + 2 * rr);
    float2 a1 = *(const float2*)(Ap0 + 2 * (rr + step));
    float2 a2 = *(const float2*)(Ap0 + 2 * (rr + 2 * step));
    float2 a3 = *(const float2*)(Ap0 + 2 * (rr + 3 * step));
    float2 b0 = *(const float2*)(Ap1 + 2 * rr);
    float2 b1 = *(const float2*)(Ap1 + 2 * (rr + step));
    float2 b2 = *(const float2*)(Ap1 + 2 * (rr + 2 * step));
    float2 b3 = *(const float2*)(Ap1 + 2 * (rr + 3 * step));
    sr0 += w * a0.x; si0 += w * a0.y; sr1 += w * a1.x; si1 += w * a1.y;
    sr2 += w * a2.x; si2 += w * a2.y; sr3 += w * a3.x; si3 += w * a3.y;
    tr0 += w * b0.x; ti0 += w * b0.y; tr1 += w * b1.x; ti1 += w * b1.y;
    tr2 += w * b2.x; ti2 += w * b2.y; tr3 += w * b3.x; ti3 += w * b3.y;
  }
  float zi = 1.f / Z;
  size_t ob0 = (size_t)k * T_LEN + t0;
  size_t ob1 = (size_t)(NK + k) * T_LEN + t0;
  out[ob0]         = sqrtf(sr0 * sr0 + si0 * si0) * zi;
  out[ob0 + 8192]  = sqrtf(sr1 * sr1 + si1 * si1) * zi;
  out[ob0 + 16384] = sqrtf(sr2 * sr2 + si2 * si2) * zi;
  out[ob0 + 24576] = sqrtf(sr3 * sr3 + si3 * si3) * zi;
  out[ob1]         = sqrtf(tr0 * tr0 + ti0 * ti0) * zi;
  out[ob1 + 8192]  = sqrtf(tr1 * tr1 + ti1 * ti1) * zi;
  out[ob1 + 16384] = sqrtf(tr2 * tr2 + ti2 * ti2) * zi;
  out[ob1 + 24576] = sqrtf(tr3 * tr3 + ti3 * ti3) * zi;
}

// ---------------- direct exact conv for j<=2 ----------------
// thread -> 4 CONSECUTIVE outputs; sliding 8-float register window; x read as
// one ds_read_b128 per 4 taps (was 16x ds_read_b32); coalesced float4 store.
__global__ __launch_bounds__(256) void k_direct(const float* __restrict__ x,
                                               const float* __restrict__ fr,
                                               const float* __restrict__ fi,
                                               float* __restrict__ out, int Lmax) {
  int k = blockIdx.y;
  int b = blockIdx.z;
  int t0 = blockIdx.x * 1024;
  int j = k >> 4, q = k & 15;
  int M = (int)ceil(6.0 * exp2((double)j + (double)q * 0.0625)) + 2; // >= true M; extra taps are 0
  int P = Lmax >> 1;
  __shared__ __align__(16) float xs[1024 + 2 * MAXM + 4];
  __shared__ __align__(16) float frs[2 * MAXM + 4], fis[2 * MAXM + 4];
  int tid = threadIdx.x;
  int xlen = 1024 + 2 * M;
  const float* xb = x + b * T_LEN;
  for (int i = tid; i < xlen; i += 256) {
    int u = t0 - M + i;
    xs[i] = (u >= 0 && u < T_LEN) ? xb[u] : 0.f;
  }
  if (tid < 4) xs[xlen + tid] = 0.f;          // zero pad (overrun reads)
  const float* frk = fr + (size_t)k * Lmax + (P - M);
  const float* fik = fi + (size_t)k * Lmax + (P - M);
  int tl = 2 * M + 1;
  for (int i = tid; i < tl; i += 256) { frs[i] = frk[i]; fis[i] = fik[i]; }
  if (tid < 3) { frs[tl + tid] = 0.f; fis[tl + tid] = 0.f; }   // zero pad
  __syncthreads();
  float ar0 = 0.f, ar1 = 0.f, ar2 = 0.f, ar3 = 0.f;
  float ai0 = 0.f, ai1 = 0.f, ai2 = 0.f, ai3 = 0.f;
  const float4* xsv = (const float4*)(xs + 4 * tid);
  float4 w0 = xsv[0];
  int groups = (tl + 3) >> 2;
  for (int g = 0; g < groups; ++g) {
    float4 w1 = xsv[g + 1];
    float4 f4 = *(const float4*)(frs + 4 * g);
    float4 h4 = *(const float4*)(fis + 4 * g);
    ar0 += f4.x * w0.x + f4.y * w0.y + f4.z * w0.z + f4.w * w0.w;
    ai0 += h4.x * w0.x + h4.y * w0.y + h4.z * w0.z + h4.w * w0.w;
    ar1 += f4.x * w0.y + f4.y * w0.z + f4.z * w0.w + f4.w * w1.x;
    ai1 += h4.x * w0.y + h4.y * w0.z + h4.z * w0.w + h4.w * w1.x;
    ar2 += f4.x * w0.z + f4.y * w0.w + f4.z * w1.x + f4.w * w1.y;
    ai2 += h4.x * w0.z + h4.y * w0.w + h4.z * w1.x + h4.w * w1.y;
    ar3 += f4.x * w0.w + f4.y * w1.x + f4.z * w1.y + f4.w * w1.z;
    ai3 += h4.x * w0.w + h4.y * w1.x + h4.z * w1.y + h4.w * w1.z;
    w0 = w1;
  }
  size_t ob = (size_t)(b * NK + k) * T_LEN + t0 + 4 * tid;
  float4 res;
  res.x = sqrtf(ar0 * ar0 + ai0 * ai0);
  res.y = sqrtf(ar1 * ar1 + ai1 * ai1);
  res.z = sqrtf(ar2 * ar2 + ai2 * ai2);
  res.w = sqrtf(ar3 * ar3 + ai3 * ai3);
  *(float4*)(out + ob) = res;
}

// ---------------- launch ----------------
extern "C" void kernel_launch(void* const* d_in, const int* in_sizes, int n_in,
                              void* d_out, int out_size, void* d_ws, size_t ws_size,
                              hipStream_t stream) {
  const float* x  = (const float*)d_in[0];
  const float* fr = (const float*)d_in[1];
  const float* fi = (const float*)d_in[2];
  float* out = (float*)d_out;
  float* ws  = (float*)d_ws;
  int Lmax = in_sizes[1] / NK;   // 47069

  // host-side geometry (pure CPU math, deterministic, graph-capture-safe)
  SParams Pm;
  int cur = 0, maxslot = 0;
  for (int ki = 0; ki < 144; ++ki) {
    int j = (ki + 48) >> 4, q = ki & 15;
    double sig = 2.0 * exp2(((double)(16 * j + q)) / 16.0);
    double s1 = sig * 0.86602540378443864676;
    int M1 = (int)ceil(3.5 * s1);
    int M1e = (M1 + 1) & ~1;
    int slotc = (2 * M1e + 2 + 511) & ~511;   // 512-granular everywhere
    Pm.m1e[ki] = M1e;
    Pm.voff[ki] = cur;
    Pm.slot[ki] = slotc;
    if (slotc > maxslot) maxslot = slotc;
    cur += 2 * slotc;
  }
  for (int j = 3; j <= 11; ++j) {
    Pm.ab[j - 3] = cur;
    cur += 32 * ((32767 >> j) + 17) * 2;   // 16q * 2b * Ncu * 2 words
  }
  // block ranges: order j = 11 down to 3; outputs-per-block per j
  const int TO[9] = {2, 3, 4, 8, 16, 64, 128, 128, 128};  // j=11..3
  Pm.jb[0] = 0;
  for (int o = 0; o < 9; ++o) {
    int j = 11 - o;
    int Ncu = (32767 >> j) + 17;
    int tiles = (Ncu + TO[o] - 1) / TO[o];
    Pm.jb[o + 1] = Pm.jb[o] + 16 * tiles;
  }

  k_vtab<<<dim3((maxslot + 1023) / 1024, 144), dim3(256), 0, stream>>>(ws, Pm);
  k_s1<<<dim3(Pm.jb[9]), dim3(256), 0, stream>>>(x, ws, Pm);
  k_direct<<<dim3(T_LEN / 1024, KDIR, NB), dim3(256), 0, stream>>>(x, fr, fi, out, Lmax);
  k_stage2<<<dim3(T_LEN / (256 * 4), NK - KDIR), dim3(256), 0, stream>>>(ws, out, Pm);
}